// Round 10
// baseline (1069.009 us; speedup 1.0000x reference)
//
#include <hip/hip_runtime.h>
#include <math.h>

#define HID 128
#define NSTEPS 64
#define SLEN 65
#define THREADS 256
#define ROWS 64
#define ASTRIDE 136   // 128 + 8 f16 pad, 16B aligned rows
#define FSTRIDE 40    // 32 + 8 f16 pad

typedef _Float16 half8 __attribute__((ext_vector_type(8)));
typedef __fp16 fp16x2 __attribute__((ext_vector_type(2)));
typedef float floatx4 __attribute__((ext_vector_type(4)));

// 2 WGs/CU (grid=512). 4 waves/WG; wave owns a 32-col N slice (wfrag=128 VGPR;
// R3: 64-col/wave spills -> x4 A-read redundancy is the VGPR-forced minimum).
// Lane owns ADJACENT cols col0,col0+1 -> b32 paired epilogue. 6 barriers/step.
// R10: residuals h0/h1 kept in f32 REGISTERS (C/D lane map identical across
// stages) -> kills residual LDS reads + improves numerics; Wf preloaded to
// registers -> kills WfS reads. LDS pipe is the bottleneck (~77% busy in R9).
__global__ __launch_bounds__(THREADS, 2)
void hedger(const float* __restrict__ S,
            const float* __restrict__ W0,  const float* __restrict__ b0,
            const float* __restrict__ rW1, const float* __restrict__ rb1,
            const float* __restrict__ rW2, const float* __restrict__ rb2,
            const float* __restrict__ sW1, const float* __restrict__ sb1,
            const float* __restrict__ sW2, const float* __restrict__ sb2,
            const float* __restrict__ Wf,  const float* __restrict__ bfp,
            float* __restrict__ out)
{
  __shared__ _Float16 bufA[ROWS * ASTRIDE];
  __shared__ _Float16 bufB[ROWS * ASTRIDE];
  __shared__ _Float16 featb[ROWS * FSTRIDE];

  const int tid  = threadIdx.x;
  const int wave = tid >> 6;            // 0..3
  const int lane = tid & 63;
  const int l15  = lane & 15;
  const int quad = lane >> 4;
  const int n_base = wave * 32;
  const int r0 = blockIdx.x * ROWS;
  const int col0 = n_base + 2 * l15;    // lane's adjacent column pair

  // ---- persistent B fragments (128 VGPR): n = col0 + nt, k = quad*8 + j.
  half8 wfrag[4][4][2];  // [matrix][kIter][nt]
  {
    const float* Wm[4] = {rW1, rW2, sW1, sW2};
#pragma unroll
    for (int m = 0; m < 4; ++m)
#pragma unroll
      for (int kq = 0; kq < 4; ++kq)
#pragma unroll
        for (int nt = 0; nt < 2; ++nt) {
          const int n  = col0 + nt;
          const int kb = kq * 32 + quad * 8;
          half8 f;
#pragma unroll
          for (int j = 0; j < 8; ++j)
            f[j] = (_Float16)Wm[m][(kb + j) * HID + n];
          wfrag[m][kq][nt] = f;
        }
  }
  // W0 (8x128) zero-padded to K=32: only quad 0 (k<8) is real.
  half8 w0frag[2];
#pragma unroll
  for (int nt = 0; nt < 2; ++nt) {
    const int n = col0 + nt;
    half8 f;
#pragma unroll
    for (int j = 0; j < 8; ++j) {
      const int k = quad * 8 + j;
      f[j] = (k < 8) ? (_Float16)W0[k * HID + n] : (_Float16)0.f;
    }
    w0frag[nt] = f;
  }
  // biases for this lane's columns
  float b0r[2], rb1r[2], rb2r[2], sb1r[2], sb2r[2];
#pragma unroll
  for (int nt = 0; nt < 2; ++nt) {
    const int n = col0 + nt;
    b0r[nt] = b0[n]; rb1r[nt] = rb1[n]; rb2r[nt] = rb2[n];
    sb1r[nt] = sb1[n]; sb2r[nt] = sb2[n];
  }
  const float bfv = bfp[0];
  // Wf slice for the final dot: this lane's quad covers cols quad*32..+31
  half8 wfv[4];
#pragma unroll
  for (int u = 0; u < 4; ++u) {
    half8 f;
#pragma unroll
    for (int j = 0; j < 8; ++j) f[j] = (_Float16)Wf[quad * 32 + u * 8 + j];
    wfv[u] = f;
  }

  // LDS zero-fill (pad cols 8..31 stay zero forever)
  for (int i = tid; i < ROWS * FSTRIDE; i += THREADS) featb[i] = (_Float16)0.f;
  __syncthreads();   // RACE FIX (R9): zero-fill completes before feature writes

  // step-0 features (threads 0..63 each own one row)
  float lm_prev = 0.f, cum_x = 0.f, qv = 0.f;
  const float* Srow = S + (size_t)(r0 + (tid & (ROWS - 1))) * SLEN;
  if (tid < ROWS) {
    const float lm = logf(Srow[0] * 0.01f);
    lm_prev = lm; cum_x = lm; qv = 0.f;
    _Float16* fr = &featb[tid * FSTRIDE];
    fr[0] = (_Float16)lm;
    fr[1] = (_Float16)1.0f;
    fr[2] = (_Float16)0.235f;
    fr[3] = (_Float16)0.f;                 // delta_0 = 0
    fr[4] = (_Float16)lm;                  // run_mean at k=0
    fr[5] = (_Float16)0.f;
    fr[6] = (_Float16)(1.9f * sqrtf(1e-12f));
    fr[7] = (_Float16)0.f;
  }
  __syncthreads();

  floatx4 acc[4][2];
  floatx4 res[4][2];   // f32 register residual (h0, then h1) — C-layout cells

#define INIT_BIAS(BR) do { \
  _Pragma("unroll") for (int mt = 0; mt < 4; ++mt) \
  _Pragma("unroll") for (int nt = 0; nt < 2; ++nt) { \
    floatx4 z = {BR[nt], BR[nt], BR[nt], BR[nt]}; acc[mt][nt] = z; } } while (0)

// acc init = bias + register residual (no LDS read)
#define INIT_BIAS_RESREG(BR) do { \
  _Pragma("unroll") for (int mt = 0; mt < 4; ++mt) \
  _Pragma("unroll") for (int nt = 0; nt < 2; ++nt) \
  _Pragma("unroll") for (int r = 0; r < 4; ++r) \
    acc[mt][nt][r] = BR[nt] + res[mt][nt][r]; } while (0)

#define GEMM128(SRC, MI) do { \
  _Pragma("unroll") for (int kq = 0; kq < 4; ++kq) { \
    half8 afr[4]; \
    _Pragma("unroll") for (int mt = 0; mt < 4; ++mt) \
      afr[mt] = *(const half8*)&SRC[(mt * 16 + l15) * ASTRIDE + kq * 32 + quad * 8]; \
    _Pragma("unroll") for (int mt = 0; mt < 4; ++mt) \
    _Pragma("unroll") for (int nt = 0; nt < 2; ++nt) \
      acc[mt][nt] = __builtin_amdgcn_mfma_f32_16x16x32_f16( \
          afr[mt], wfrag[MI][kq][nt], acc[mt][nt], 0, 0, 0); \
  } } while (0)

// lrelu in f32, RTN casts, pack pair -> one b32 store
#define EPI_LRELU(DST) do { \
  _Pragma("unroll") for (int mt = 0; mt < 4; ++mt) \
  _Pragma("unroll") for (int r = 0; r < 4; ++r) { \
    const int row = mt * 16 + quad * 4 + r; \
    const float v0 = acc[mt][0][r]; \
    const float v1 = acc[mt][1][r]; \
    fp16x2 h2 = {(__fp16)fmaxf(v0, 0.2f * v0), (__fp16)fmaxf(v1, 0.2f * v1)}; \
    *(fp16x2*)&DST[row * ASTRIDE + col0] = h2; \
  } } while (0)

// lrelu + keep f32 result in res (residual source)
#define EPI_LRELU_KEEP(DST) do { \
  _Pragma("unroll") for (int mt = 0; mt < 4; ++mt) \
  _Pragma("unroll") for (int r = 0; r < 4; ++r) { \
    const int row = mt * 16 + quad * 4 + r; \
    const float l0 = fmaxf(acc[mt][0][r], 0.2f * acc[mt][0][r]); \
    const float l1 = fmaxf(acc[mt][1][r], 0.2f * acc[mt][1][r]); \
    res[mt][0][r] = l0; res[mt][1][r] = l1; \
    fp16x2 h2 = {(__fp16)l0, (__fp16)l1}; \
    *(fp16x2*)&DST[row * ASTRIDE + col0] = h2; \
  } } while (0)

// store f16 + keep f32 acc in res (h1 residual for the s-block)
#define EPI_STORE_KEEP(DST) do { \
  _Pragma("unroll") for (int mt = 0; mt < 4; ++mt) \
  _Pragma("unroll") for (int r = 0; r < 4; ++r) { \
    const int row = mt * 16 + quad * 4 + r; \
    res[mt][0][r] = acc[mt][0][r]; res[mt][1][r] = acc[mt][1][r]; \
    fp16x2 h2 = {(__fp16)acc[mt][0][r], (__fp16)acc[mt][1][r]}; \
    *(fp16x2*)&DST[row * ASTRIDE + col0] = h2; \
  } } while (0)

#define EPI_STORE(DST) do { \
  _Pragma("unroll") for (int mt = 0; mt < 4; ++mt) \
  _Pragma("unroll") for (int r = 0; r < 4; ++r) { \
    const int row = mt * 16 + quad * 4 + r; \
    fp16x2 h2 = {(__fp16)acc[mt][0][r], (__fp16)acc[mt][1][r]}; \
    *(fp16x2*)&DST[row * ASTRIDE + col0] = h2; \
  } } while (0)

#pragma unroll 1
  for (int k = 0; k < NSTEPS; ++k) {
    // G0: h0 = lrelu(featPad @ W0pad + b0)   (featb complete: fr[3] via bar F)
    INIT_BIAS(b0r);
    {
      half8 afr[4];
#pragma unroll
      for (int mt = 0; mt < 4; ++mt)
        afr[mt] = *(const half8*)&featb[(mt * 16 + l15) * FSTRIDE + quad * 8];
#pragma unroll
      for (int mt = 0; mt < 4; ++mt)
#pragma unroll
        for (int nt = 0; nt < 2; ++nt)
          acc[mt][nt] = __builtin_amdgcn_mfma_f32_16x16x32_f16(
              afr[mt], w0frag[nt], acc[mt][nt], 0, 0, 0);
    }
    EPI_LRELU_KEEP(bufA);                              // res = f32 h0
    __syncthreads();                                   // bar A: bufA ready, featb consumed

    // delta-independent features of step k+1 — overlaps the GEMM phase.
    // (Srow[k+1] valid at k=63: SLEN=65; write is dead then, harmless.)
    if (tid < ROWS) {
      const int kk = k + 1;
      const float lm = logf(Srow[kk] * 0.01f);
      const float rr = lm - lm_prev; qv += rr * rr;
      lm_prev = lm; cum_x += lm;
      const float tT = (float)kk * (1.f / 64.f);
      _Float16* fr = &featb[tid * FSTRIDE];
      fr[0] = (_Float16)lm;
      fr[1] = (_Float16)(1.f - tT);
      fr[4] = (_Float16)(cum_x / (float)(kk + 1));
      fr[5] = (_Float16)qv;
      fr[6] = (_Float16)(1.9f * sqrtf(qv + 1e-12f));
      fr[7] = (_Float16)tT;
    }

    INIT_BIAS(rb1r);        GEMM128(bufA, 0); EPI_LRELU(bufB);      // u
    __syncthreads();                                   // bar B
    INIT_BIAS_RESREG(rb2r); GEMM128(bufB, 1); EPI_STORE_KEEP(bufA); // h1 (res=f32 h1)
    __syncthreads();                                   // bar C
    INIT_BIAS(sb1r);        GEMM128(bufA, 2); EPI_LRELU(bufB);      // v
    __syncthreads();                                   // bar D
    INIT_BIAS_RESREG(sb2r); GEMM128(bufB, 3); EPI_STORE(bufA);      // h2
    __syncthreads();                                   // bar E: h2 in bufA

    // delta = sigmoid(h2 @ Wf + bf); wave covers 16 rows, quads split K.
    // f32-convert + FMA; Wf from registers (wfv).
    {
      const int row = wave * 16 + l15;
      const _Float16* hr = &bufA[row * ASTRIDE + quad * 32];
      float s = 0.f;
#pragma unroll
      for (int u = 0; u < 4; ++u) {
        const half8 h = *(const half8*)&hr[u * 8];
        const half8 w = wfv[u];
#pragma unroll
        for (int j = 0; j < 8; ++j) s += (float)h[j] * (float)w[j];
      }
      s += __shfl_xor(s, 16);
      s += __shfl_xor(s, 32);
      const float d = 1.f / (1.f + expf(-(s + bfv)));
      if (quad == 0) {
        featb[row * FSTRIDE + 3] = (_Float16)d;        // fr[3] for step k+1
        out[(size_t)(r0 + row) * NSTEPS + k] = d;
      }
    }
    __syncthreads();                                   // bar F: featb complete
  }
#undef INIT_BIAS
#undef INIT_BIAS_RESREG
#undef GEMM128
#undef EPI_LRELU
#undef EPI_LRELU_KEEP
#undef EPI_STORE_KEEP
#undef EPI_STORE
}

extern "C" void kernel_launch(void* const* d_in, const int* in_sizes, int n_in,
                              void* d_out, int out_size, void* d_ws, size_t ws_size,
                              hipStream_t stream) {
  const float* S   = (const float*)d_in[0];
  const float* W0  = (const float*)d_in[1];
  const float* b0  = (const float*)d_in[2];
  const float* rW1 = (const float*)d_in[3];
  const float* rb1 = (const float*)d_in[4];
  const float* rW2 = (const float*)d_in[5];
  const float* rb2 = (const float*)d_in[6];
  const float* sW1 = (const float*)d_in[7];
  const float* sb1 = (const float*)d_in[8];
  const float* sW2 = (const float*)d_in[9];
  const float* sb2 = (const float*)d_in[10];
  const float* Wf  = (const float*)d_in[11];
  const float* bf  = (const float*)d_in[12];
  float* out = (float*)d_out;

  const int B = out_size / NSTEPS;        // 32768
  const int nblocks = B / ROWS;           // 512 WGs -> 2 per CU
  hedger<<<nblocks, THREADS, 0, stream>>>(
      S, W0, b0, rW1, rb1, rW2, rb2, sW1, sb1, sW2, sb2, Wf, bf, out);
}

// Round 11
// 494.471 us; speedup vs baseline: 2.1619x; 2.1619x over previous
//
#include <hip/hip_runtime.h>
#include <math.h>

#define HID 128
#define NSTEPS 64
#define SLEN 65
#define THREADS 256
#define ROWS 64
#define ASTRIDE 136   // 128 + 8 f16 pad, 16B aligned rows
#define FSTRIDE 40    // 32 + 8 f16 pad

typedef _Float16 half8 __attribute__((ext_vector_type(8)));
typedef __fp16 fp16x2 __attribute__((ext_vector_type(2)));
typedef float floatx4 __attribute__((ext_vector_type(4)));

// 2 WGs/CU (grid=512). 4 waves/WG; wave owns a 32-col N slice (wfrag=128 VGPR;
// R3: 64-col/wave spills). Lane owns ADJACENT cols col0,col0+1.
// R10 lesson: +48 VGPRs of long-lived state (f32 res + wfv) spills to scratch
// (FETCH 16MB -> 1.1GB). R11: residual kept as PACKED fp16x2 (+16 VGPR only),
// bit-identical to R9's LDS round-trip value; Wf stays in LDS. Kills the
// 32 b32 residual reads/lane/step (~10% of the LDS-bound step).
__global__ __launch_bounds__(THREADS, 2)
void hedger(const float* __restrict__ S,
            const float* __restrict__ W0,  const float* __restrict__ b0,
            const float* __restrict__ rW1, const float* __restrict__ rb1,
            const float* __restrict__ rW2, const float* __restrict__ rb2,
            const float* __restrict__ sW1, const float* __restrict__ sb1,
            const float* __restrict__ sW2, const float* __restrict__ sb2,
            const float* __restrict__ Wf,  const float* __restrict__ bfp,
            float* __restrict__ out)
{
  __shared__ _Float16 bufA[ROWS * ASTRIDE];
  __shared__ _Float16 bufB[ROWS * ASTRIDE];
  __shared__ _Float16 featb[ROWS * FSTRIDE];
  __shared__ _Float16 WfS[HID];

  const int tid  = threadIdx.x;
  const int wave = tid >> 6;            // 0..3
  const int lane = tid & 63;
  const int l15  = lane & 15;
  const int quad = lane >> 4;
  const int n_base = wave * 32;
  const int r0 = blockIdx.x * ROWS;
  const int col0 = n_base + 2 * l15;    // lane's adjacent column pair

  // ---- persistent B fragments (128 VGPR): n = col0 + nt, k = quad*8 + j.
  half8 wfrag[4][4][2];  // [matrix][kIter][nt]
  {
    const float* Wm[4] = {rW1, rW2, sW1, sW2};
#pragma unroll
    for (int m = 0; m < 4; ++m)
#pragma unroll
      for (int kq = 0; kq < 4; ++kq)
#pragma unroll
        for (int nt = 0; nt < 2; ++nt) {
          const int n  = col0 + nt;
          const int kb = kq * 32 + quad * 8;
          half8 f;
#pragma unroll
          for (int j = 0; j < 8; ++j)
            f[j] = (_Float16)Wm[m][(kb + j) * HID + n];
          wfrag[m][kq][nt] = f;
        }
  }
  // W0 (8x128) zero-padded to K=32: only quad 0 (k<8) is real.
  half8 w0frag[2];
#pragma unroll
  for (int nt = 0; nt < 2; ++nt) {
    const int n = col0 + nt;
    half8 f;
#pragma unroll
    for (int j = 0; j < 8; ++j) {
      const int k = quad * 8 + j;
      f[j] = (k < 8) ? (_Float16)W0[k * HID + n] : (_Float16)0.f;
    }
    w0frag[nt] = f;
  }
  // biases for this lane's columns
  float b0r[2], rb1r[2], rb2r[2], sb1r[2], sb2r[2];
#pragma unroll
  for (int nt = 0; nt < 2; ++nt) {
    const int n = col0 + nt;
    b0r[nt] = b0[n]; rb1r[nt] = rb1[n]; rb2r[nt] = rb2[n];
    sb1r[nt] = sb1[n]; sb2r[nt] = sb2[n];
  }
  const float bfv = bfp[0];

  // LDS zero-fill (pad cols 8..31 stay zero forever) + Wf
  for (int i = tid; i < ROWS * FSTRIDE; i += THREADS) featb[i] = (_Float16)0.f;
  if (tid < HID) WfS[tid] = (_Float16)Wf[tid];
  __syncthreads();   // RACE FIX (R9): zero-fill completes before feature writes

  // step-0 features (threads 0..63 each own one row)
  float lm_prev = 0.f, cum_x = 0.f, qv = 0.f;
  const float* Srow = S + (size_t)(r0 + (tid & (ROWS - 1))) * SLEN;
  if (tid < ROWS) {
    const float lm = logf(Srow[0] * 0.01f);
    lm_prev = lm; cum_x = lm; qv = 0.f;
    _Float16* fr = &featb[tid * FSTRIDE];
    fr[0] = (_Float16)lm;
    fr[1] = (_Float16)1.0f;
    fr[2] = (_Float16)0.235f;
    fr[3] = (_Float16)0.f;                 // delta_0 = 0
    fr[4] = (_Float16)lm;                  // run_mean at k=0
    fr[5] = (_Float16)0.f;
    fr[6] = (_Float16)(1.9f * sqrtf(1e-12f));
    fr[7] = (_Float16)0.f;
  }
  __syncthreads();

  floatx4 acc[4][2];
  fp16x2 resp[4][4];   // packed f16 residual [mt][r] — same bits as the LDS value

#define INIT_BIAS(BR) do { \
  _Pragma("unroll") for (int mt = 0; mt < 4; ++mt) \
  _Pragma("unroll") for (int nt = 0; nt < 2; ++nt) { \
    floatx4 z = {BR[nt], BR[nt], BR[nt], BR[nt]}; acc[mt][nt] = z; } } while (0)

// acc init = bias + packed-register residual (no LDS read; bits == R9's read)
#define INIT_BIAS_RESREG(BR) do { \
  _Pragma("unroll") for (int mt = 0; mt < 4; ++mt) \
  _Pragma("unroll") for (int r = 0; r < 4; ++r) { \
    acc[mt][0][r] = BR[0] + (float)resp[mt][r][0]; \
    acc[mt][1][r] = BR[1] + (float)resp[mt][r][1]; \
  } } while (0)

#define GEMM128(SRC, MI) do { \
  _Pragma("unroll") for (int kq = 0; kq < 4; ++kq) { \
    half8 afr[4]; \
    _Pragma("unroll") for (int mt = 0; mt < 4; ++mt) \
      afr[mt] = *(const half8*)&SRC[(mt * 16 + l15) * ASTRIDE + kq * 32 + quad * 8]; \
    _Pragma("unroll") for (int mt = 0; mt < 4; ++mt) \
    _Pragma("unroll") for (int nt = 0; nt < 2; ++nt) \
      acc[mt][nt] = __builtin_amdgcn_mfma_f32_16x16x32_f16( \
          afr[mt], wfrag[MI][kq][nt], acc[mt][nt], 0, 0, 0); \
  } } while (0)

// lrelu in f32, RTN casts, pack pair -> one b32 store
#define EPI_LRELU(DST) do { \
  _Pragma("unroll") for (int mt = 0; mt < 4; ++mt) \
  _Pragma("unroll") for (int r = 0; r < 4; ++r) { \
    const int row = mt * 16 + quad * 4 + r; \
    const float v0 = acc[mt][0][r]; \
    const float v1 = acc[mt][1][r]; \
    fp16x2 h2 = {(__fp16)fmaxf(v0, 0.2f * v0), (__fp16)fmaxf(v1, 0.2f * v1)}; \
    *(fp16x2*)&DST[row * ASTRIDE + col0] = h2; \
  } } while (0)

// lrelu + keep packed f16 in resp (residual source)
#define EPI_LRELU_KEEP(DST) do { \
  _Pragma("unroll") for (int mt = 0; mt < 4; ++mt) \
  _Pragma("unroll") for (int r = 0; r < 4; ++r) { \
    const int row = mt * 16 + quad * 4 + r; \
    const float v0 = acc[mt][0][r]; \
    const float v1 = acc[mt][1][r]; \
    fp16x2 h2 = {(__fp16)fmaxf(v0, 0.2f * v0), (__fp16)fmaxf(v1, 0.2f * v1)}; \
    resp[mt][r] = h2; \
    *(fp16x2*)&DST[row * ASTRIDE + col0] = h2; \
  } } while (0)

// store f16 + keep packed f16 in resp (h1 residual for the s-block)
#define EPI_STORE_KEEP(DST) do { \
  _Pragma("unroll") for (int mt = 0; mt < 4; ++mt) \
  _Pragma("unroll") for (int r = 0; r < 4; ++r) { \
    const int row = mt * 16 + quad * 4 + r; \
    fp16x2 h2 = {(__fp16)acc[mt][0][r], (__fp16)acc[mt][1][r]}; \
    resp[mt][r] = h2; \
    *(fp16x2*)&DST[row * ASTRIDE + col0] = h2; \
  } } while (0)

#define EPI_STORE(DST) do { \
  _Pragma("unroll") for (int mt = 0; mt < 4; ++mt) \
  _Pragma("unroll") for (int r = 0; r < 4; ++r) { \
    const int row = mt * 16 + quad * 4 + r; \
    fp16x2 h2 = {(__fp16)acc[mt][0][r], (__fp16)acc[mt][1][r]}; \
    *(fp16x2*)&DST[row * ASTRIDE + col0] = h2; \
  } } while (0)

#pragma unroll 1
  for (int k = 0; k < NSTEPS; ++k) {
    // G0: h0 = lrelu(featPad @ W0pad + b0)   (featb complete: fr[3] via bar F)
    INIT_BIAS(b0r);
    {
      half8 afr[4];
#pragma unroll
      for (int mt = 0; mt < 4; ++mt)
        afr[mt] = *(const half8*)&featb[(mt * 16 + l15) * FSTRIDE + quad * 8];
#pragma unroll
      for (int mt = 0; mt < 4; ++mt)
#pragma unroll
        for (int nt = 0; nt < 2; ++nt)
          acc[mt][nt] = __builtin_amdgcn_mfma_f32_16x16x32_f16(
              afr[mt], w0frag[nt], acc[mt][nt], 0, 0, 0);
    }
    EPI_LRELU_KEEP(bufA);                              // resp = h0 (f16 bits)
    __syncthreads();                                   // bar A: bufA ready, featb consumed

    // delta-independent features of step k+1 — overlaps the GEMM phase.
    // (Srow[k+1] valid at k=63: SLEN=65; write is dead then, harmless.)
    if (tid < ROWS) {
      const int kk = k + 1;
      const float lm = logf(Srow[kk] * 0.01f);
      const float rr = lm - lm_prev; qv += rr * rr;
      lm_prev = lm; cum_x += lm;
      const float tT = (float)kk * (1.f / 64.f);
      _Float16* fr = &featb[tid * FSTRIDE];
      fr[0] = (_Float16)lm;
      fr[1] = (_Float16)(1.f - tT);
      fr[4] = (_Float16)(cum_x / (float)(kk + 1));
      fr[5] = (_Float16)qv;
      fr[6] = (_Float16)(1.9f * sqrtf(qv + 1e-12f));
      fr[7] = (_Float16)tT;
    }

    INIT_BIAS(rb1r);        GEMM128(bufA, 0); EPI_LRELU(bufB);      // u
    __syncthreads();                                   // bar B
    INIT_BIAS_RESREG(rb2r); GEMM128(bufB, 1); EPI_STORE_KEEP(bufA); // h1 (resp=h1)
    __syncthreads();                                   // bar C
    INIT_BIAS(sb1r);        GEMM128(bufA, 2); EPI_LRELU(bufB);      // v
    __syncthreads();                                   // bar D
    INIT_BIAS_RESREG(sb2r); GEMM128(bufB, 3); EPI_STORE(bufA);      // h2
    __syncthreads();                                   // bar E: h2 in bufA

    // delta = sigmoid(h2 @ Wf + bf); wave covers 16 rows, quads split K.
    // f32-convert + FMA (R4/R9 numerics).
    {
      const int row = wave * 16 + l15;
      const _Float16* hr = &bufA[row * ASTRIDE + quad * 32];
      const _Float16* wr = &WfS[quad * 32];
      float s = 0.f;
#pragma unroll
      for (int u = 0; u < 4; ++u) {
        const half8 h = *(const half8*)&hr[u * 8];
        const half8 w = *(const half8*)&wr[u * 8];
#pragma unroll
        for (int j = 0; j < 8; ++j) s += (float)h[j] * (float)w[j];
      }
      s += __shfl_xor(s, 16);
      s += __shfl_xor(s, 32);
      const float d = 1.f / (1.f + expf(-(s + bfv)));
      if (quad == 0) {
        featb[row * FSTRIDE + 3] = (_Float16)d;        // fr[3] for step k+1
        out[(size_t)(r0 + row) * NSTEPS + k] = d;
      }
    }
    __syncthreads();                                   // bar F: featb complete
  }
#undef INIT_BIAS
#undef INIT_BIAS_RESREG
#undef GEMM128
#undef EPI_LRELU
#undef EPI_LRELU_KEEP
#undef EPI_STORE_KEEP
#undef EPI_STORE
}

extern "C" void kernel_launch(void* const* d_in, const int* in_sizes, int n_in,
                              void* d_out, int out_size, void* d_ws, size_t ws_size,
                              hipStream_t stream) {
  const float* S   = (const float*)d_in[0];
  const float* W0  = (const float*)d_in[1];
  const float* b0  = (const float*)d_in[2];
  const float* rW1 = (const float*)d_in[3];
  const float* rb1 = (const float*)d_in[4];
  const float* rW2 = (const float*)d_in[5];
  const float* rb2 = (const float*)d_in[6];
  const float* sW1 = (const float*)d_in[7];
  const float* sb1 = (const float*)d_in[8];
  const float* sW2 = (const float*)d_in[9];
  const float* sb2 = (const float*)d_in[10];
  const float* Wf  = (const float*)d_in[11];
  const float* bf  = (const float*)d_in[12];
  float* out = (float*)d_out;

  const int B = out_size / NSTEPS;        // 32768
  const int nblocks = B / ROWS;           // 512 WGs -> 2 per CU
  hedger<<<nblocks, THREADS, 0, stream>>>(
      S, W0, b0, rW1, rb1, rW2, rb2, sW1, sb1, sW2, sb2, Wf, bf, out);
}

// Round 12
// 413.962 us; speedup vs baseline: 2.5824x; 1.1945x over previous
//
#include <hip/hip_runtime.h>
#include <math.h>

#define HID 128
#define NSTEPS 64
#define SLEN 65
#define THREADS 256
#define ROWS 64
#define ASTRIDE 136   // 128 + 8 f16 pad, 16B aligned rows
#define FSTRIDE 40    // 32 + 8 f16 pad

typedef _Float16 half8 __attribute__((ext_vector_type(8)));
typedef __fp16 fp16x2 __attribute__((ext_vector_type(2)));
typedef float floatx4 __attribute__((ext_vector_type(4)));

// R12 = R9 exact revert (best verified: 390 us, absmax 3.9e-3).
// Structure: 2 WGs/CU (grid=512), 4 waves/WG, wave owns a 32-col N slice
// (wfrag=128 VGPR), lane owns adjacent col pair -> b32 paired LDS epilogue,
// 6 barriers/step, k+1 delta-independent features overlap the GEMM phase.
// CLOSED paths (evidence): residual-in-registers spills at +16 VGPR (R11:
// WRITE 172MB) and +48 (R10: 1.3GB); 64-col/wave spills (R3: 5.3GB); 3 WG/CU
// needs <=170 VGPR -> spill; 32x32 MFMA -> scalar-b16 epilogue, worse LDS;
// barriers: 6 = dependency minimum; SQ_LDS_BANK_CONFLICT 3.8e7 intrinsic to
// strided ds_read_b128 A-fragments (invariant R1/R2/R4/R9; halves with
// per-wave A-reads in R3). VGPR_Count CSV field does NOT reflect spill —
// watch FETCH/WRITE_SIZE instead.
__global__ __launch_bounds__(THREADS, 2)
void hedger(const float* __restrict__ S,
            const float* __restrict__ W0,  const float* __restrict__ b0,
            const float* __restrict__ rW1, const float* __restrict__ rb1,
            const float* __restrict__ rW2, const float* __restrict__ rb2,
            const float* __restrict__ sW1, const float* __restrict__ sb1,
            const float* __restrict__ sW2, const float* __restrict__ sb2,
            const float* __restrict__ Wf,  const float* __restrict__ bfp,
            float* __restrict__ out)
{
  __shared__ _Float16 bufA[ROWS * ASTRIDE];
  __shared__ _Float16 bufB[ROWS * ASTRIDE];
  __shared__ _Float16 featb[ROWS * FSTRIDE];
  __shared__ _Float16 WfS[HID];

  const int tid  = threadIdx.x;
  const int wave = tid >> 6;            // 0..3
  const int lane = tid & 63;
  const int l15  = lane & 15;
  const int quad = lane >> 4;
  const int n_base = wave * 32;
  const int r0 = blockIdx.x * ROWS;
  const int col0 = n_base + 2 * l15;    // lane's adjacent column pair

  // ---- persistent B fragments (128 VGPR): n = col0 + nt, k = quad*8 + j.
  half8 wfrag[4][4][2];  // [matrix][kIter][nt]
  {
    const float* Wm[4] = {rW1, rW2, sW1, sW2};
#pragma unroll
    for (int m = 0; m < 4; ++m)
#pragma unroll
      for (int kq = 0; kq < 4; ++kq)
#pragma unroll
        for (int nt = 0; nt < 2; ++nt) {
          const int n  = col0 + nt;
          const int kb = kq * 32 + quad * 8;
          half8 f;
#pragma unroll
          for (int j = 0; j < 8; ++j)
            f[j] = (_Float16)Wm[m][(kb + j) * HID + n];
          wfrag[m][kq][nt] = f;
        }
  }
  // W0 (8x128) zero-padded to K=32: only quad 0 (k<8) is real.
  half8 w0frag[2];
#pragma unroll
  for (int nt = 0; nt < 2; ++nt) {
    const int n = col0 + nt;
    half8 f;
#pragma unroll
    for (int j = 0; j < 8; ++j) {
      const int k = quad * 8 + j;
      f[j] = (k < 8) ? (_Float16)W0[k * HID + n] : (_Float16)0.f;
    }
    w0frag[nt] = f;
  }
  // biases for this lane's columns
  float b0r[2], rb1r[2], rb2r[2], sb1r[2], sb2r[2];
#pragma unroll
  for (int nt = 0; nt < 2; ++nt) {
    const int n = col0 + nt;
    b0r[nt] = b0[n]; rb1r[nt] = rb1[n]; rb2r[nt] = rb2[n];
    sb1r[nt] = sb1[n]; sb2r[nt] = sb2[n];
  }
  const float bfv = bfp[0];

  // LDS zero-fill (pad cols 8..31 stay zero forever) + Wf
  for (int i = tid; i < ROWS * FSTRIDE; i += THREADS) featb[i] = (_Float16)0.f;
  if (tid < HID) WfS[tid] = (_Float16)Wf[tid];
  __syncthreads();   // RACE FIX (R9): zero-fill completes before feature writes

  // step-0 features (threads 0..63 each own one row)
  float lm_prev = 0.f, cum_x = 0.f, qv = 0.f;
  const float* Srow = S + (size_t)(r0 + (tid & (ROWS - 1))) * SLEN;
  if (tid < ROWS) {
    const float lm = logf(Srow[0] * 0.01f);
    lm_prev = lm; cum_x = lm; qv = 0.f;
    _Float16* fr = &featb[tid * FSTRIDE];
    fr[0] = (_Float16)lm;
    fr[1] = (_Float16)1.0f;
    fr[2] = (_Float16)0.235f;
    fr[3] = (_Float16)0.f;                 // delta_0 = 0
    fr[4] = (_Float16)lm;                  // run_mean at k=0
    fr[5] = (_Float16)0.f;
    fr[6] = (_Float16)(1.9f * sqrtf(1e-12f));
    fr[7] = (_Float16)0.f;
  }
  __syncthreads();

  floatx4 acc[4][2];

#define INIT_BIAS(BR) do { \
  _Pragma("unroll") for (int mt = 0; mt < 4; ++mt) \
  _Pragma("unroll") for (int nt = 0; nt < 2; ++nt) { \
    floatx4 z = {BR[nt], BR[nt], BR[nt], BR[nt]}; acc[mt][nt] = z; } } while (0)

#define INIT_BIAS_RES(BR, RESBUF) do { \
  _Pragma("unroll") for (int mt = 0; mt < 4; ++mt) \
  _Pragma("unroll") for (int r = 0; r < 4; ++r) { \
    const int row = mt * 16 + quad * 4 + r; \
    const fp16x2 h2 = *(const fp16x2*)&RESBUF[row * ASTRIDE + col0]; \
    acc[mt][0][r] = BR[0] + (float)h2[0]; \
    acc[mt][1][r] = BR[1] + (float)h2[1]; \
  } } while (0)

#define GEMM128(SRC, MI) do { \
  _Pragma("unroll") for (int kq = 0; kq < 4; ++kq) { \
    half8 afr[4]; \
    _Pragma("unroll") for (int mt = 0; mt < 4; ++mt) \
      afr[mt] = *(const half8*)&SRC[(mt * 16 + l15) * ASTRIDE + kq * 32 + quad * 8]; \
    _Pragma("unroll") for (int mt = 0; mt < 4; ++mt) \
    _Pragma("unroll") for (int nt = 0; nt < 2; ++nt) \
      acc[mt][nt] = __builtin_amdgcn_mfma_f32_16x16x32_f16( \
          afr[mt], wfrag[MI][kq][nt], acc[mt][nt], 0, 0, 0); \
  } } while (0)

// lrelu in f32, RTN casts, pack pair -> one b32 store
#define EPI_LRELU(DST) do { \
  _Pragma("unroll") for (int mt = 0; mt < 4; ++mt) \
  _Pragma("unroll") for (int r = 0; r < 4; ++r) { \
    const int row = mt * 16 + quad * 4 + r; \
    const float v0 = acc[mt][0][r]; \
    const float v1 = acc[mt][1][r]; \
    fp16x2 h2 = {(__fp16)fmaxf(v0, 0.2f * v0), (__fp16)fmaxf(v1, 0.2f * v1)}; \
    *(fp16x2*)&DST[row * ASTRIDE + col0] = h2; \
  } } while (0)

#define EPI_STORE(DST) do { \
  _Pragma("unroll") for (int mt = 0; mt < 4; ++mt) \
  _Pragma("unroll") for (int r = 0; r < 4; ++r) { \
    const int row = mt * 16 + quad * 4 + r; \
    fp16x2 h2 = {(__fp16)acc[mt][0][r], (__fp16)acc[mt][1][r]}; \
    *(fp16x2*)&DST[row * ASTRIDE + col0] = h2; \
  } } while (0)

#pragma unroll 1
  for (int k = 0; k < NSTEPS; ++k) {
    // G0: h0 = lrelu(featPad @ W0pad + b0)   (featb complete: fr[3] via bar F)
    INIT_BIAS(b0r);
    {
      half8 afr[4];
#pragma unroll
      for (int mt = 0; mt < 4; ++mt)
        afr[mt] = *(const half8*)&featb[(mt * 16 + l15) * FSTRIDE + quad * 8];
#pragma unroll
      for (int mt = 0; mt < 4; ++mt)
#pragma unroll
        for (int nt = 0; nt < 2; ++nt)
          acc[mt][nt] = __builtin_amdgcn_mfma_f32_16x16x32_f16(
              afr[mt], w0frag[nt], acc[mt][nt], 0, 0, 0);
    }
    EPI_LRELU(bufA);
    __syncthreads();                                   // bar A: bufA ready, featb consumed

    // delta-independent features of step k+1 — overlaps the GEMM phase.
    // (Srow[k+1] valid at k=63: SLEN=65; write is dead then, harmless.)
    if (tid < ROWS) {
      const int kk = k + 1;
      const float lm = logf(Srow[kk] * 0.01f);
      const float rr = lm - lm_prev; qv += rr * rr;
      lm_prev = lm; cum_x += lm;
      const float tT = (float)kk * (1.f / 64.f);
      _Float16* fr = &featb[tid * FSTRIDE];
      fr[0] = (_Float16)lm;
      fr[1] = (_Float16)(1.f - tT);
      fr[4] = (_Float16)(cum_x / (float)(kk + 1));
      fr[5] = (_Float16)qv;
      fr[6] = (_Float16)(1.9f * sqrtf(qv + 1e-12f));
      fr[7] = (_Float16)tT;
    }

    INIT_BIAS(rb1r);            GEMM128(bufA, 0); EPI_LRELU(bufB);  // u
    __syncthreads();                                   // bar B
    INIT_BIAS_RES(rb2r, bufA);  GEMM128(bufB, 1); EPI_STORE(bufA);  // h1
    __syncthreads();                                   // bar C
    INIT_BIAS(sb1r);            GEMM128(bufA, 2); EPI_LRELU(bufB);  // v
    __syncthreads();                                   // bar D
    INIT_BIAS_RES(sb2r, bufA);  GEMM128(bufB, 3); EPI_STORE(bufA);  // h2
    __syncthreads();                                   // bar E: h2 in bufA

    // delta = sigmoid(h2 @ Wf + bf); wave covers 16 rows, quads split K.
    // f32-convert + FMA (R4/R9 numerics).
    {
      const int row = wave * 16 + l15;
      const _Float16* hr = &bufA[row * ASTRIDE + quad * 32];
      const _Float16* wr = &WfS[quad * 32];
      float s = 0.f;
#pragma unroll
      for (int u = 0; u < 4; ++u) {
        const half8 h = *(const half8*)&hr[u * 8];
        const half8 w = *(const half8*)&wr[u * 8];
#pragma unroll
        for (int j = 0; j < 8; ++j) s += (float)h[j] * (float)w[j];
      }
      s += __shfl_xor(s, 16);
      s += __shfl_xor(s, 32);
      const float d = 1.f / (1.f + expf(-(s + bfv)));
      if (quad == 0) {
        featb[row * FSTRIDE + 3] = (_Float16)d;        // fr[3] for step k+1
        out[(size_t)(r0 + row) * NSTEPS + k] = d;
      }
    }
    __syncthreads();                                   // bar F: featb complete
  }
#undef INIT_BIAS
#undef INIT_BIAS_RES
#undef GEMM128
#undef EPI_LRELU
#undef EPI_STORE
}

extern "C" void kernel_launch(void* const* d_in, const int* in_sizes, int n_in,
                              void* d_out, int out_size, void* d_ws, size_t ws_size,
                              hipStream_t stream) {
  const float* S   = (const float*)d_in[0];
  const float* W0  = (const float*)d_in[1];
  const float* b0  = (const float*)d_in[2];
  const float* rW1 = (const float*)d_in[3];
  const float* rb1 = (const float*)d_in[4];
  const float* rW2 = (const float*)d_in[5];
  const float* rb2 = (const float*)d_in[6];
  const float* sW1 = (const float*)d_in[7];
  const float* sb1 = (const float*)d_in[8];
  const float* sW2 = (const float*)d_in[9];
  const float* sb2 = (const float*)d_in[10];
  const float* Wf  = (const float*)d_in[11];
  const float* bf  = (const float*)d_in[12];
  float* out = (float*)d_out;

  const int B = out_size / NSTEPS;        // 32768
  const int nblocks = B / ROWS;           // 512 WGs -> 2 per CU
  hedger<<<nblocks, THREADS, 0, stream>>>(
      S, W0, b0, rW1, rb1, rW2, rb2, sW1, sb1, sW2, sb2, Wf, bf, out);
}